// Round 10
// baseline (36.410 us; speedup 1.0000x reference)
//
#include <hip/hip_runtime.h>

#define BB 4
#define SS 4096
#define EE 128

typedef __attribute__((ext_vector_type(8))) short bf16x8;
typedef __attribute__((ext_vector_type(4))) float f32x4;

__device__ __forceinline__ unsigned short f2bf(float f) {
    unsigned u = __float_as_uint(f);
    u = (u + 0x7FFFu + ((u >> 16) & 1u)) >> 16;
    return (unsigned short)u;
}
__device__ __forceinline__ float bf2f(unsigned short h) {
    return __uint_as_float(((unsigned)h) << 16);
}
__device__ __forceinline__ void split8(const float* p, bf16x8& h, bf16x8& l) {
    float4 v0 = *reinterpret_cast<const float4*>(p);
    float4 v1 = *reinterpret_cast<const float4*>(p + 4);
    float f[8] = {v0.x, v0.y, v0.z, v0.w, v1.x, v1.y, v1.z, v1.w};
    #pragma unroll
    for (int i = 0; i < 8; ++i) {
        unsigned short hb = f2bf(f[i]);
        h[i] = (short)hb;
        l[i] = (short)f2bf(f[i] - bf2f(hb));
    }
}
__device__ __forceinline__ void split8r(const float* f, bf16x8& h, bf16x8& l) {
    #pragma unroll
    for (int i = 0; i < 8; ++i) {
        unsigned short hb = f2bf(f[i]);
        h[i] = (short)hb;
        l[i] = (short)f2bf(f[i] - bf2f(hb));
    }
}
// 3-product split-bf16 MFMA: ~f32 accuracy (drops lo*lo)
__device__ __forceinline__ f32x4 mfma3(bf16x8 ah, bf16x8 al, bf16x8 bh, bf16x8 bl, f32x4 c) {
    c = __builtin_amdgcn_mfma_f32_16x16x32_bf16(ah, bh, c, 0, 0, 0);
    c = __builtin_amdgcn_mfma_f32_16x16x32_bf16(al, bh, c, 0, 0, 0);
    c = __builtin_amdgcn_mfma_f32_16x16x32_bf16(ah, bl, c, 0, 0, 0);
    return c;
}

// ---------------------------------------------------------------------------
// K1 prep (r9, unchanged): blocks [0,256): vpart producer;
//   blocks [256,260): per-batch all-MFMA special producer (K -> Mt hi/lo, Vt).
// ---------------------------------------------------------------------------
__global__ __launch_bounds__(256, 2)
void prep(const float* __restrict__ x, const float* __restrict__ Wk,
          const float* __restrict__ Wq, const float* __restrict__ Wv,
          unsigned short* __restrict__ Vt,
          unsigned short* __restrict__ Mth, unsigned short* __restrict__ Mtl,
          float* __restrict__ vpart)
{
    __shared__ float ksub[64][68];
    const int tid = threadIdx.x;
    const int bx = blockIdx.x;

    if (bx < 256) {
        float* xred = &ksub[0][0];   // [0:128) rg0, [128:256) rg1, [256:384) xsum
        const int b = bx >> 6, i = bx & 63;
        const size_t base = ((size_t)b * SS + 64 + (size_t)i * 63) * EE;
        const int col = tid & 127, rg = tid >> 7;
        float s = 0.f;
        for (int r = rg; r < 63; r += 2)
            s += x[base + (size_t)r * EE + col];
        xred[rg * 128 + col] = s;
        __syncthreads();
        if (tid < 128) xred[256 + tid] = xred[tid] + xred[128 + tid];
        __syncthreads();
        if (tid < 128) {
            float a = 0.f;
            #pragma unroll 8
            for (int e = 0; e < 128; e += 4) {
                float4 wv = *reinterpret_cast<const float4*>(Wv + (size_t)tid * EE + e);
                a = fmaf(xred[256 + e + 0], wv.x, a);
                a = fmaf(xred[256 + e + 1], wv.y, a);
                a = fmaf(xred[256 + e + 2], wv.z, a);
                a = fmaf(xred[256 + e + 3], wv.w, a);
            }
            vpart[((size_t)b * 64 + i) * 128 + tid] = a;
        }
        return;
    }

    const int b = bx - 256;
    const int l = tid & 63, w = tid >> 6;
    const int lm = l & 15, lg = l >> 4;
    const int t0 = w * 16;

    float wq_raw[2][2][8];
    #pragma unroll
    for (int eti = 0; eti < 2; ++eti)
        #pragma unroll
        for (int kt2 = 0; kt2 < 2; ++kt2) {
            const int e = 32 * w + 16 * eti + lm;
            const int j0 = kt2 * 32 + lg * 8;
            #pragma unroll
            for (int i = 0; i < 8; ++i)
                wq_raw[eti][kt2][i] = Wq[(size_t)(j0 + i) * EE + e];
        }

    bf16x8 xh[4], xl[4];
    const float* xrow = x + ((size_t)b * SS + t0 + lm) * EE + lg * 8;
    #pragma unroll
    for (int kt = 0; kt < 4; ++kt)
        split8(xrow + kt * 32, xh[kt], xl[kt]);

    #pragma unroll
    for (int jt = 0; jt < 4; ++jt) {
        f32x4 a = {0.f, 0.f, 0.f, 0.f};
        const float* wkr = Wk + (size_t)(jt * 16 + lm) * EE + lg * 8;
        #pragma unroll
        for (int kt = 0; kt < 4; ++kt) {
            bf16x8 bh, bl;
            split8(wkr + kt * 32, bh, bl);
            a = mfma3(xh[kt], xl[kt], bh, bl, a);
        }
        const int j = jt * 16 + lm;
        #pragma unroll
        for (int r = 0; r < 4; ++r) {
            const int t = t0 + lg * 4 + r;
            ksub[t][j] = (t <= j) ? a[r] : 0.f;
        }
    }
    __syncthreads();

    bf16x8 ah[2][2], al[2][2];
    #pragma unroll
    for (int eti = 0; eti < 2; ++eti)
        #pragma unroll
        for (int kt2 = 0; kt2 < 2; ++kt2)
            split8r(&wq_raw[eti][kt2][0], ah[eti][kt2], al[eti][kt2]);
    #pragma unroll
    for (int eti = 0; eti < 2; ++eti)
        #pragma unroll
        for (int tt = 0; tt < 4; ++tt) {
            f32x4 a = {0.f, 0.f, 0.f, 0.f};
            #pragma unroll
            for (int kt2 = 0; kt2 < 2; ++kt2) {
                bf16x8 bh, bl;
                split8(&ksub[tt * 16 + lm][kt2 * 32 + lg * 8], bh, bl);
                a = mfma3(ah[eti][kt2], al[eti][kt2], bh, bl, a);
            }
            const int t = tt * 16 + lm;
            const int e0 = 32 * w + 16 * eti + lg * 4;
            unsigned short h0 = f2bf(a[0]), h1 = f2bf(a[1]);
            unsigned short h2 = f2bf(a[2]), h3 = f2bf(a[3]);
            ushort4 hv = make_ushort4(h0, h1, h2, h3);
            ushort4 lv = make_ushort4(f2bf(a[0] - bf2f(h0)), f2bf(a[1] - bf2f(h1)),
                                      f2bf(a[2] - bf2f(h2)), f2bf(a[3] - bf2f(h3)));
            const size_t off = (size_t)b * 8192 + (size_t)t * 128 + e0;
            *reinterpret_cast<ushort4*>(Mth + off) = hv;
            *reinterpret_cast<ushort4*>(Mtl + off) = lv;
        }

    #pragma unroll
    for (int vt = 0; vt < 8; ++vt) {
        f32x4 a = {0.f, 0.f, 0.f, 0.f};
        const float* wvr = Wv + (size_t)(vt * 16 + lm) * EE + lg * 8;
        #pragma unroll
        for (int kt = 0; kt < 4; ++kt) {
            bf16x8 bh, bl;
            split8(wvr + kt * 32, bh, bl);
            a = mfma3(xh[kt], xl[kt], bh, bl, a);
        }
        const int v = vt * 16 + lm;
        ushort4 pk = make_ushort4(f2bf(a[0]), f2bf(a[1]), f2bf(a[2]), f2bf(a[3]));
        *reinterpret_cast<ushort4*>(Vt + (size_t)b * 8192 + (size_t)v * 64 + t0 + lg * 4) = pk;
    }
}

// ---------------------------------------------------------------------------
// K2 attn_main (r6 shape, 1024 blocks x 1 wave = 4 blocks/CU): vsum prologue
// (64 fixed-order vpart partials), S = x@Mt split-MFMA, softmax (+4032
// zero-col term), P relayout via LDS, PV MFMA + vsum term + store.
// ---------------------------------------------------------------------------
__global__ __launch_bounds__(64)
void attn_main(const float* __restrict__ x, const short* __restrict__ Mth,
               const short* __restrict__ Mtl, const short* __restrict__ Vt,
               const float* __restrict__ vpart, float* __restrict__ out)
{
    __shared__ float Plds[16][68];
    __shared__ float vsS[128];
    const int l = threadIdx.x;
    const int b = blockIdx.y;
    const int s0 = blockIdx.x * 16;
    const int lm = l & 15, lg = l >> 4;

    // vsum reduction: lane owns cols (2l, 2l+1); needed only at the end
    float2 vac = make_float2(0.f, 0.f);
    {
        const float* vp = vpart + (size_t)b * 8192 + 2 * l;
        #pragma unroll 8
        for (int i = 0; i < 64; ++i) {
            float2 t = *reinterpret_cast<const float2*>(vp + (size_t)i * 128);
            vac.x += t.x; vac.y += t.y;
        }
    }
    *reinterpret_cast<float2*>(&vsS[2 * l]) = vac;

    // x A-frags (hi/lo split)
    bf16x8 xh[4], xl[4];
    const float* xrow = x + ((size_t)b * SS + s0 + lm) * EE + lg * 8;
    #pragma unroll
    for (int kt = 0; kt < 4; ++kt)
        split8(xrow + kt * 32, xh[kt], xl[kt]);

    // S = x @ Mt : 4 col-tiles x (4 k-tiles x 3 split-mfma)
    f32x4 sa[4];
    const short* mh_base = Mth + (size_t)b * 8192 + lg * 8;
    const short* ml_base = Mtl + (size_t)b * 8192 + lg * 8;
    #pragma unroll
    for (int ct = 0; ct < 4; ++ct) {
        f32x4 a = {0.f, 0.f, 0.f, 0.f};
        const size_t trow = (size_t)(ct * 16 + lm) * 128;
        #pragma unroll
        for (int kt = 0; kt < 4; ++kt) {
            bf16x8 mh = *reinterpret_cast<const bf16x8*>(mh_base + trow + kt * 32);
            bf16x8 ml = *reinterpret_cast<const bf16x8*>(ml_base + trow + kt * 32);
            a = __builtin_amdgcn_mfma_f32_16x16x32_bf16(xh[kt], mh, a, 0, 0, 0);
            a = __builtin_amdgcn_mfma_f32_16x16x32_bf16(xl[kt], mh, a, 0, 0, 0);
            a = __builtin_amdgcn_mfma_f32_16x16x32_bf16(xh[kt], ml, a, 0, 0, 0);
        }
        sa[ct] = a;
    }

    // softmax over 4096 cols (64 real + 4032 exact zeros)
    float e[4], iz[4];
    #pragma unroll
    for (int r = 0; r < 4; ++r) {
        float m = fmaxf(fmaxf(sa[0][r], sa[1][r]), fmaxf(sa[2][r], sa[3][r]));
        #pragma unroll
        for (int o = 1; o < 16; o <<= 1) m = fmaxf(m, __shfl_xor(m, o));
        m = fmaxf(m, 0.f);
        float w0 = __expf(sa[0][r] - m), w1 = __expf(sa[1][r] - m);
        float w2 = __expf(sa[2][r] - m), w3 = __expf(sa[3][r] - m);
        sa[0][r] = w0; sa[1][r] = w1; sa[2][r] = w2; sa[3][r] = w3;
        float z = (w0 + w1) + (w2 + w3);
        #pragma unroll
        for (int o = 1; o < 16; o <<= 1) z += __shfl_xor(z, o);
        e[r] = __expf(-m);
        z += 4032.f * e[r];
        iz[r] = 1.f / z;
    }

    // P relayout: C/D layout -> A-frag layout via LDS
    #pragma unroll
    for (int ct = 0; ct < 4; ++ct)
        #pragma unroll
        for (int r = 0; r < 4; ++r)
            Plds[lg * 4 + r][ct * 16 + lm] = sa[ct][r];
    bf16x8 pf[2];
    #pragma unroll
    for (int kt2 = 0; kt2 < 2; ++kt2) {
        const float* pr = &Plds[lm][kt2 * 32 + lg * 8];
        #pragma unroll
        for (int i = 0; i < 8; ++i) pf[kt2][i] = (short)f2bf(pr[i]);
    }

    // PV + vsum term + normalize + store
    const short* vb = Vt + (size_t)b * 8192 + lg * 8;
    const size_t obase = ((size_t)b * SS + s0) * EE;
    #pragma unroll
    for (int ct = 0; ct < 8; ++ct) {
        const int col = ct * 16 + lm;
        bf16x8 v0 = *reinterpret_cast<const bf16x8*>(vb + (size_t)col * 64);
        bf16x8 v1 = *reinterpret_cast<const bf16x8*>(vb + (size_t)col * 64 + 32);
        f32x4 a = {0.f, 0.f, 0.f, 0.f};
        a = __builtin_amdgcn_mfma_f32_16x16x32_bf16(pf[0], v0, a, 0, 0, 0);
        a = __builtin_amdgcn_mfma_f32_16x16x32_bf16(pf[1], v1, a, 0, 0, 0);
        const float vs = vsS[col];
        #pragma unroll
        for (int r = 0; r < 4; ++r)
            out[obase + (size_t)(lg * 4 + r) * EE + col] = (a[r] + e[r] * vs) * iz[r];
    }
}

// ---------------------------------------------------------------------------
extern "C" void kernel_launch(void* const* d_in, const int* in_sizes, int n_in,
                              void* d_out, int out_size, void* d_ws, size_t ws_size,
                              hipStream_t stream)
{
    const float* x  = (const float*)d_in[0];
    const float* Wk = (const float*)d_in[1];
    const float* Wq = (const float*)d_in[2];
    const float* Wv = (const float*)d_in[3];
    float* out = (float*)d_out;

    float* vpart = (float*)d_ws;                            // 4*64*128 f32
    unsigned short* Mth = (unsigned short*)(vpart + 32768); // 4*64*128 bf16
    unsigned short* Mtl = Mth + 32768;                      // 4*64*128 bf16
    unsigned short* Vt  = Mtl + 32768;                      // 4*128*64 bf16

    prep<<<260, 256, 0, stream>>>(x, Wk, Wq, Wv, Vt, Mth, Mtl, vpart);
    attn_main<<<dim3(SS / 16, BB), 64, 0, stream>>>(
        x, (const short*)Mth, (const short*)Mtl, (const short*)Vt, vpart, out);
}

// Round 11
// 30.086 us; speedup vs baseline: 1.2102x; 1.2102x over previous
//
#include <hip/hip_runtime.h>

#define BB 4
#define SS 4096
#define EE 128

typedef __attribute__((ext_vector_type(8))) short bf16x8;
typedef __attribute__((ext_vector_type(4))) float f32x4;

__device__ __forceinline__ unsigned short f2bf(float f) {
    unsigned u = __float_as_uint(f);
    u = (u + 0x7FFFu + ((u >> 16) & 1u)) >> 16;
    return (unsigned short)u;
}
__device__ __forceinline__ float bf2f(unsigned short h) {
    return __uint_as_float(((unsigned)h) << 16);
}
__device__ __forceinline__ void split8(const float* p, bf16x8& h, bf16x8& l) {
    float4 v0 = *reinterpret_cast<const float4*>(p);
    float4 v1 = *reinterpret_cast<const float4*>(p + 4);
    float f[8] = {v0.x, v0.y, v0.z, v0.w, v1.x, v1.y, v1.z, v1.w};
    #pragma unroll
    for (int i = 0; i < 8; ++i) {
        unsigned short hb = f2bf(f[i]);
        h[i] = (short)hb;
        l[i] = (short)f2bf(f[i] - bf2f(hb));
    }
}

// ---------------------------------------------------------------------------
// prep1: blocks [0,256): xpart[b][i][c] = sum of x[b, 64+i*63 .. +63, c]
//        blocks [256,268): per (b, role) 64x64 GEMM on x[b,0:64]:
//          role 0/1: Vt[b][v][t] = bf16( x64 @ Wv^T )  (transposed store)
//          role 2:   key64T[b][j][t] = (t<=j) ? x64[t].Wk[j] : 0   (f32)
// ---------------------------------------------------------------------------
__global__ __launch_bounds__(256, 2)
void prep1(const float* __restrict__ x, const float* __restrict__ Wk,
           const float* __restrict__ Wv,
           unsigned short* __restrict__ Vt, float* __restrict__ key64T,
           float* __restrict__ xpart)
{
    __shared__ float xs[64][132];
    __shared__ float wst[128][68];
    const int tid = threadIdx.x;
    const int bx = blockIdx.x;

    if (bx < 256) {
        __shared__ float xred[2][128];
        const int b = bx >> 6, i = bx & 63;
        const size_t base = ((size_t)b * SS + 64 + (size_t)i * 63) * EE;
        const int col = tid & 127, rg = tid >> 7;
        float s = 0.f;
        for (int r = rg; r < 63; r += 2)
            s += x[base + (size_t)r * EE + col];
        xred[rg][col] = s;
        __syncthreads();
        if (tid < 128)
            xpart[((size_t)b * 64 + i) * 128 + tid] = xred[0][tid] + xred[1][tid];
        return;
    }

    const int idx = bx - 256;
    const int b = idx / 3, role = idx % 3;
    const size_t xrow0 = (size_t)b * SS;
    const float* Wbase = (role == 0) ? Wv : (role == 1) ? (Wv + 64 * EE) : Wk;

    #pragma unroll
    for (int i = 0; i < 8; ++i) {
        int f4 = tid + i * 256;
        int row = f4 >> 5, kq = f4 & 31;
        float4 v = *reinterpret_cast<const float4*>(x + (xrow0 + row) * EE + 4 * kq);
        *reinterpret_cast<float4*>(&xs[row][4 * kq]) = v;
    }
    #pragma unroll
    for (int i = 0; i < 8; ++i) {
        int f4 = tid + i * 256;
        int c = f4 & 63, kq = f4 >> 6;
        float4 v = *reinterpret_cast<const float4*>(Wbase + (size_t)c * EE + 4 * kq);
        wst[4 * kq + 0][c] = v.x;
        wst[4 * kq + 1][c] = v.y;
        wst[4 * kq + 2][c] = v.z;
        wst[4 * kq + 3][c] = v.w;
    }
    __syncthreads();

    const int ct = tid & 15, rt = tid >> 4;
    const int c0 = 4 * ct, r0 = 4 * rt;
    float acc[4][4] = {};
    #pragma unroll 4
    for (int k0 = 0; k0 < 128; k0 += 4) {
        float4 a[4], bq[4];
        #pragma unroll
        for (int i = 0; i < 4; ++i) a[i] = *reinterpret_cast<const float4*>(&xs[r0 + i][k0]);
        #pragma unroll
        for (int kk = 0; kk < 4; ++kk) bq[kk] = *reinterpret_cast<const float4*>(&wst[k0 + kk][c0]);
        #pragma unroll
        for (int i = 0; i < 4; ++i) {
            const float4 ai = a[i];
            acc[i][0] = fmaf(ai.x, bq[0].x, acc[i][0]);
            acc[i][1] = fmaf(ai.x, bq[0].y, acc[i][1]);
            acc[i][2] = fmaf(ai.x, bq[0].z, acc[i][2]);
            acc[i][3] = fmaf(ai.x, bq[0].w, acc[i][3]);
            acc[i][0] = fmaf(ai.y, bq[1].x, acc[i][0]);
            acc[i][1] = fmaf(ai.y, bq[1].y, acc[i][1]);
            acc[i][2] = fmaf(ai.y, bq[1].z, acc[i][2]);
            acc[i][3] = fmaf(ai.y, bq[1].w, acc[i][3]);
            acc[i][0] = fmaf(ai.z, bq[2].x, acc[i][0]);
            acc[i][1] = fmaf(ai.z, bq[2].y, acc[i][1]);
            acc[i][2] = fmaf(ai.z, bq[2].z, acc[i][2]);
            acc[i][3] = fmaf(ai.z, bq[2].w, acc[i][3]);
            acc[i][0] = fmaf(ai.w, bq[3].x, acc[i][0]);
            acc[i][1] = fmaf(ai.w, bq[3].y, acc[i][1]);
            acc[i][2] = fmaf(ai.w, bq[3].z, acc[i][2]);
            acc[i][3] = fmaf(ai.w, bq[3].w, acc[i][3]);
        }
    }

    if (role <= 1) {
        const int voff = role * 64;
        #pragma unroll
        for (int j = 0; j < 4; ++j) {
            ushort4 pk = make_ushort4(f2bf(acc[0][j]), f2bf(acc[1][j]),
                                      f2bf(acc[2][j]), f2bf(acc[3][j]));
            *reinterpret_cast<ushort4*>(Vt + (size_t)b * 8192 + (size_t)(voff + c0 + j) * 64 + r0) = pk;
        }
    } else {
        #pragma unroll
        for (int i = 0; i < 4; ++i)
            #pragma unroll
            for (int j = 0; j < 4; ++j) {
                const int t = r0 + i, k = c0 + j;
                key64T[((size_t)b * 64 + k) * 64 + t] = (t <= k) ? acc[i][j] : 0.f;
            }
    }
}

// ---------------------------------------------------------------------------
// prep2: blocks [0,16): b=bx>>2, k-quarter kq=bx&3:
//   Mt[b][t][k] = sum_j Wq[j][k] * key64T[b][j][t]  -> bf16 hi/lo (transposed)
//        blocks [16,20): vsum[b] = (sum_i xpart[b][i]) @ Wv^T   (f32)
// ---------------------------------------------------------------------------
__global__ __launch_bounds__(256)
void prep2(const float* __restrict__ Wq, const float* __restrict__ Wv,
           const float* __restrict__ key64T, const float* __restrict__ xpart,
           unsigned short* __restrict__ Mth, unsigned short* __restrict__ Mtl,
           float* __restrict__ vsum)
{
    const int tid = threadIdx.x, bx = blockIdx.x;
    if (bx < 16) {
        __shared__ float ks[64][66];
        __shared__ float wqs[64][36];
        const int b = bx >> 2, kq = bx & 3;
        #pragma unroll
        for (int i = 0; i < 4; ++i) {
            int f4 = tid + i * 256;
            int j = f4 >> 4, t4 = f4 & 15;
            float4 v = *reinterpret_cast<const float4*>(key64T + (size_t)b * 4096 + (size_t)j * 64 + 4 * t4);
            *reinterpret_cast<float4*>(&ks[j][4 * t4]) = v;
        }
        #pragma unroll
        for (int i = 0; i < 2; ++i) {
            int f4 = tid + i * 256;
            int j = f4 >> 3, kk = f4 & 7;
            float4 v = *reinterpret_cast<const float4*>(Wq + (size_t)j * EE + kq * 32 + 4 * kk);
            *reinterpret_cast<float4*>(&wqs[j][4 * kk]) = v;
        }
        __syncthreads();
        const int t0 = (tid >> 3) * 2, k0 = (tid & 7) * 4;
        float acc[2][4] = {};
        #pragma unroll
        for (int j = 0; j < 64; ++j) {
            float4 w4 = *reinterpret_cast<const float4*>(&wqs[j][k0]);
            float kv0 = ks[j][t0], kv1 = ks[j][t0 + 1];
            acc[0][0] = fmaf(kv0, w4.x, acc[0][0]);
            acc[0][1] = fmaf(kv0, w4.y, acc[0][1]);
            acc[0][2] = fmaf(kv0, w4.z, acc[0][2]);
            acc[0][3] = fmaf(kv0, w4.w, acc[0][3]);
            acc[1][0] = fmaf(kv1, w4.x, acc[1][0]);
            acc[1][1] = fmaf(kv1, w4.y, acc[1][1]);
            acc[1][2] = fmaf(kv1, w4.z, acc[1][2]);
            acc[1][3] = fmaf(kv1, w4.w, acc[1][3]);
        }
        #pragma unroll
        for (int dt = 0; dt < 2; ++dt) {
            unsigned short h0 = f2bf(acc[dt][0]), h1 = f2bf(acc[dt][1]);
            unsigned short h2 = f2bf(acc[dt][2]), h3 = f2bf(acc[dt][3]);
            ushort4 hv = make_ushort4(h0, h1, h2, h3);
            ushort4 lv = make_ushort4(f2bf(acc[dt][0] - bf2f(h0)),
                                      f2bf(acc[dt][1] - bf2f(h1)),
                                      f2bf(acc[dt][2] - bf2f(h2)),
                                      f2bf(acc[dt][3] - bf2f(h3)));
            const size_t off = (size_t)b * 8192 + (size_t)(t0 + dt) * 128 + kq * 32 + k0;
            *reinterpret_cast<ushort4*>(Mth + off) = hv;
            *reinterpret_cast<ushort4*>(Mtl + off) = lv;
        }
    } else {
        __shared__ float xsum[128];
        const int b = bx - 16;
        if (tid < 128) {
            float s = 0.f;
            #pragma unroll 8
            for (int i = 0; i < 64; ++i) s += xpart[((size_t)b * 64 + i) * 128 + tid];
            xsum[tid] = s;
        }
        __syncthreads();
        if (tid < 128) {
            float a = 0.f;
            #pragma unroll 8
            for (int e = 0; e < 128; e += 4) {
                float4 w = *reinterpret_cast<const float4*>(Wv + (size_t)tid * EE + e);
                a = fmaf(xsum[e + 0], w.x, a);
                a = fmaf(xsum[e + 1], w.y, a);
                a = fmaf(xsum[e + 2], w.z, a);
                a = fmaf(xsum[e + 3], w.w, a);
            }
            vsum[(size_t)b * EE + tid] = a;
        }
    }
}

// ---------------------------------------------------------------------------
// main: 1 wave per block, 16 q-rows. S = x@M via split-bf16 MFMA (3x),
// in-register softmax (+ 4032 zero-col term), P relayout via 4KB LDS,
// out = P@V (bf16 MFMA) + e*vsum, normalized.
// ---------------------------------------------------------------------------
__global__ __launch_bounds__(64)
void attn_main(const float* __restrict__ x, const short* __restrict__ Mth,
               const short* __restrict__ Mtl, const short* __restrict__ Vt,
               const float* __restrict__ vsum, float* __restrict__ out)
{
    __shared__ float Plds[16][68];
    const int l = threadIdx.x;
    const int b = blockIdx.y;
    const int s0 = blockIdx.x * 16;
    const int lm = l & 15, lg = l >> 4;

    // ---- x A-frags (hi/lo split) ----
    bf16x8 xh[4], xl[4];
    const float* xrow = x + ((size_t)b * SS + s0 + lm) * EE + lg * 8;
    #pragma unroll
    for (int kt = 0; kt < 4; ++kt)
        split8(xrow + kt * 32, xh[kt], xl[kt]);

    // ---- S = x @ M : 4 col-tiles x (4 k-tiles x 3 split-mfma) ----
    f32x4 sa[4];
    const short* mh_base = Mth + (size_t)b * 8192 + lg * 8;
    const short* ml_base = Mtl + (size_t)b * 8192 + lg * 8;
    #pragma unroll
    for (int ct = 0; ct < 4; ++ct) {
        f32x4 a = {0.f, 0.f, 0.f, 0.f};
        const size_t trow = (size_t)(ct * 16 + lm) * 128;
        #pragma unroll
        for (int kt = 0; kt < 4; ++kt) {
            bf16x8 mh = *reinterpret_cast<const bf16x8*>(mh_base + trow + kt * 32);
            bf16x8 ml = *reinterpret_cast<const bf16x8*>(ml_base + trow + kt * 32);
            a = __builtin_amdgcn_mfma_f32_16x16x32_bf16(xh[kt], mh, a, 0, 0, 0);
            a = __builtin_amdgcn_mfma_f32_16x16x32_bf16(xl[kt], mh, a, 0, 0, 0);
            a = __builtin_amdgcn_mfma_f32_16x16x32_bf16(xh[kt], ml, a, 0, 0, 0);
        }
        sa[ct] = a;
    }

    // ---- softmax over 4096 cols (64 real + 4032 exact zeros) ----
    float e[4], iz[4];
    #pragma unroll
    for (int r = 0; r < 4; ++r) {
        float m = fmaxf(fmaxf(sa[0][r], sa[1][r]), fmaxf(sa[2][r], sa[3][r]));
        #pragma unroll
        for (int o = 1; o < 16; o <<= 1) m = fmaxf(m, __shfl_xor(m, o));
        m = fmaxf(m, 0.f);
        float w0 = __expf(sa[0][r] - m), w1 = __expf(sa[1][r] - m);
        float w2 = __expf(sa[2][r] - m), w3 = __expf(sa[3][r] - m);
        sa[0][r] = w0; sa[1][r] = w1; sa[2][r] = w2; sa[3][r] = w3;
        float z = (w0 + w1) + (w2 + w3);
        #pragma unroll
        for (int o = 1; o < 16; o <<= 1) z += __shfl_xor(z, o);
        e[r] = __expf(-m);
        z += 4032.f * e[r];
        iz[r] = 1.f / z;
    }

    // ---- P relayout: C/D layout -> A-frag layout via LDS ----
    #pragma unroll
    for (int ct = 0; ct < 4; ++ct)
        #pragma unroll
        for (int r = 0; r < 4; ++r)
            Plds[lg * 4 + r][ct * 16 + lm] = sa[ct][r];
    bf16x8 pf[2];
    #pragma unroll
    for (int kt2 = 0; kt2 < 2; ++kt2) {
        const float* pr = &Plds[lm][kt2 * 32 + lg * 8];
        #pragma unroll
        for (int i = 0; i < 8; ++i) pf[kt2][i] = (short)f2bf(pr[i]);
    }

    // ---- PV + vsum term + normalize + store ----
    const short* vb = Vt + (size_t)b * 8192 + lg * 8;
    const float* vsb = vsum + (size_t)b * EE;
    const size_t obase = ((size_t)b * SS + s0) * EE;
    #pragma unroll
    for (int ct = 0; ct < 8; ++ct) {
        const int col = ct * 16 + lm;
        bf16x8 v0 = *reinterpret_cast<const bf16x8*>(vb + (size_t)col * 64);
        bf16x8 v1 = *reinterpret_cast<const bf16x8*>(vb + (size_t)col * 64 + 32);
        f32x4 a = {0.f, 0.f, 0.f, 0.f};
        a = __builtin_amdgcn_mfma_f32_16x16x32_bf16(pf[0], v0, a, 0, 0, 0);
        a = __builtin_amdgcn_mfma_f32_16x16x32_bf16(pf[1], v1, a, 0, 0, 0);
        const float vs = vsb[col];
        #pragma unroll
        for (int r = 0; r < 4; ++r)
            out[obase + (size_t)(lg * 4 + r) * EE + col] = (a[r] + e[r] * vs) * iz[r];
    }
}

// ---------------------------------------------------------------------------
extern "C" void kernel_launch(void* const* d_in, const int* in_sizes, int n_in,
                              void* d_out, int out_size, void* d_ws, size_t ws_size,
                              hipStream_t stream)
{
    const float* x  = (const float*)d_in[0];
    const float* Wk = (const float*)d_in[1];
    const float* Wq = (const float*)d_in[2];
    const float* Wv = (const float*)d_in[3];
    float* out = (float*)d_out;

    float* ws = (float*)d_ws;
    float* key64T = ws;                       // 4*64*64   = 16384 f32
    float* xpart  = key64T + 16384;           // 4*64*128  = 32768 f32
    float* vsum   = xpart + 32768;            // 4*128     = 512 f32
    unsigned short* Mth = (unsigned short*)(vsum + 512);   // 4*64*128 bf16
    unsigned short* Mtl = Mth + 32768;                     // 4*64*128 bf16
    unsigned short* Vt  = Mtl + 32768;                     // 4*128*64 bf16

    prep1<<<268, 256, 0, stream>>>(x, Wk, Wv, Vt, key64T, xpart);
    prep2<<<20, 256, 0, stream>>>(Wq, Wv, key64T, xpart, Mth, Mtl, vsum);
    attn_main<<<dim3(SS / 16, BB), 64, 0, stream>>>(
        x, (const short*)Mth, (const short*)Mtl, (const short*)Vt, vsum, out);
}

// Round 12
// 27.814 us; speedup vs baseline: 1.3091x; 1.0817x over previous
//
#include <hip/hip_runtime.h>

#define BB 4
#define SS 4096
#define EE 128

typedef __attribute__((ext_vector_type(8))) short bf16x8;
typedef __attribute__((ext_vector_type(4))) float f32x4;

__device__ __forceinline__ unsigned short f2bf(float f) {
    unsigned u = __float_as_uint(f);
    u = (u + 0x7FFFu + ((u >> 16) & 1u)) >> 16;
    return (unsigned short)u;
}
__device__ __forceinline__ float bf2f(unsigned short h) {
    return __uint_as_float(((unsigned)h) << 16);
}
// round-to-nearest split (proven path, used by attn_main / prep2)
__device__ __forceinline__ void split8(const float* p, bf16x8& h, bf16x8& l) {
    float4 v0 = *reinterpret_cast<const float4*>(p);
    float4 v1 = *reinterpret_cast<const float4*>(p + 4);
    float f[8] = {v0.x, v0.y, v0.z, v0.w, v1.x, v1.y, v1.z, v1.w};
    #pragma unroll
    for (int i = 0; i < 8; ++i) {
        unsigned short hb = f2bf(f[i]);
        h[i] = (short)hb;
        l[i] = (short)f2bf(f[i] - bf2f(hb));
    }
}
// cheap truncating split (~4 VALU/elem): hi = trunc, lo absorbs, lo truncated.
// product error ~2^-16 rel (vs 2^-17 for rounded) — inside budget.
__device__ __forceinline__ void split8t(const float* p, bf16x8& h, bf16x8& l) {
    float4 v0 = *reinterpret_cast<const float4*>(p);
    float4 v1 = *reinterpret_cast<const float4*>(p + 4);
    float f[8] = {v0.x, v0.y, v0.z, v0.w, v1.x, v1.y, v1.z, v1.w};
    #pragma unroll
    for (int i = 0; i < 8; ++i) {
        unsigned hb = __float_as_uint(f[i]) >> 16;
        h[i] = (short)hb;
        float lo = f[i] - __uint_as_float(hb << 16);
        l[i] = (short)(__float_as_uint(lo) >> 16);
    }
}
// 3-product split-bf16 MFMA: ~f32 accuracy (drops lo*lo)
__device__ __forceinline__ f32x4 mfma3(bf16x8 ah, bf16x8 al, bf16x8 bh, bf16x8 bl, f32x4 c) {
    c = __builtin_amdgcn_mfma_f32_16x16x32_bf16(ah, bh, c, 0, 0, 0);
    c = __builtin_amdgcn_mfma_f32_16x16x32_bf16(al, bh, c, 0, 0, 0);
    c = __builtin_amdgcn_mfma_f32_16x16x32_bf16(ah, bl, c, 0, 0, 0);
    return c;
}

// ---------------------------------------------------------------------------
// prep1: blocks [0,256): xpart[b][i][c] = sum of x[b, 64+i*63 .. +63, c]
//        blocks [256,268): idx=bx-256, b=idx/3, role=idx%3: MFMA 64x64 GEMM
//          on x[b,0:64] with ROW-MAJOR LDS staging (2-way banks, free):
//          role 0/1: Vt[b][v][t] = bf16( x64 @ Wv^T )  (transposed store)
//          role 2:   key64T[b][j][t] = (t<=j) ? x64[t].Wk[j] : 0   (f32)
// ---------------------------------------------------------------------------
__global__ __launch_bounds__(256, 2)
void prep1(const float* __restrict__ x, const float* __restrict__ Wk,
           const float* __restrict__ Wv,
           unsigned short* __restrict__ Vt, float* __restrict__ key64T,
           float* __restrict__ xpart)
{
    __shared__ float xs[64][132];
    __shared__ float ws[64][132];
    const int tid = threadIdx.x;
    const int bx = blockIdx.x;

    if (bx < 256) {
        __shared__ float xred[2][128];
        const int b = bx >> 6, i = bx & 63;
        const size_t base = ((size_t)b * SS + 64 + (size_t)i * 63) * EE;
        const int col = tid & 127, rg = tid >> 7;
        float s = 0.f;
        for (int r = rg; r < 63; r += 2)
            s += x[base + (size_t)r * EE + col];
        xred[rg][col] = s;
        __syncthreads();
        if (tid < 128)
            xpart[((size_t)b * 64 + i) * 128 + tid] = xred[0][tid] + xred[1][tid];
        return;
    }

    const int idx = bx - 256;
    const int b = idx / 3, role = idx % 3;
    const float* Wbase = (role == 0) ? Wv : (role == 1) ? (Wv + 64 * EE) : Wk;

    // stage x64 and W rows, row-major, fully coalesced
    #pragma unroll
    for (int i = 0; i < 8; ++i) {
        int f4 = tid + i * 256;
        int row = f4 >> 5, kq = f4 & 31;
        *reinterpret_cast<float4*>(&xs[row][4 * kq]) =
            *reinterpret_cast<const float4*>(x + ((size_t)b * SS + row) * EE + 4 * kq);
    }
    #pragma unroll
    for (int i = 0; i < 8; ++i) {
        int f4 = tid + i * 256;
        int row = f4 >> 5, kq = f4 & 31;
        *reinterpret_cast<float4*>(&ws[row][4 * kq]) =
            *reinterpret_cast<const float4*>(Wbase + (size_t)row * EE + 4 * kq);
    }
    __syncthreads();

    const int l = tid & 63, w = tid >> 6;
    const int lm = l & 15, lg = l >> 4;
    const int t0 = w * 16;              // wave's 16 output rows (t)

    // A-frags: x rows, split once, reused across all 4 col-tiles
    bf16x8 xh[4], xl[4];
    #pragma unroll
    for (int kt = 0; kt < 4; ++kt)
        split8(&xs[t0 + lm][kt * 32 + lg * 8], xh[kt], xl[kt]);

    #pragma unroll
    for (int ct = 0; ct < 4; ++ct) {
        f32x4 a = {0.f, 0.f, 0.f, 0.f};
        #pragma unroll
        for (int kt = 0; kt < 4; ++kt) {
            bf16x8 bh, bl;
            split8t(&ws[ct * 16 + lm][kt * 32 + lg * 8], bh, bl);
            a = mfma3(xh[kt], xl[kt], bh, bl, a);
        }
        const int col = ct * 16 + lm;   // D: row t0+lg*4+r, col
        if (role <= 1) {
            const int voff = role * 64;
            ushort4 pk = make_ushort4(f2bf(a[0]), f2bf(a[1]), f2bf(a[2]), f2bf(a[3]));
            *reinterpret_cast<ushort4*>(Vt + (size_t)b * 8192 +
                                        (size_t)(voff + col) * 64 + t0 + lg * 4) = pk;
        } else {
            const int tb = t0 + lg * 4;
            float4 kv = make_float4((tb + 0 <= col) ? a[0] : 0.f,
                                    (tb + 1 <= col) ? a[1] : 0.f,
                                    (tb + 2 <= col) ? a[2] : 0.f,
                                    (tb + 3 <= col) ? a[3] : 0.f);
            *reinterpret_cast<float4*>(key64T + ((size_t)b * 64 + col) * 64 + tb) = kv;
        }
    }
}

// ---------------------------------------------------------------------------
// prep2 (r11, unchanged): blocks [0,16): Mt[b][t][k] bf16 hi/lo from key64T;
//        blocks [16,20): vsum[b] = (sum_i xpart[b][i]) @ Wv^T  (f32)
// ---------------------------------------------------------------------------
__global__ __launch_bounds__(256)
void prep2(const float* __restrict__ Wq, const float* __restrict__ Wv,
           const float* __restrict__ key64T, const float* __restrict__ xpart,
           unsigned short* __restrict__ Mth, unsigned short* __restrict__ Mtl,
           float* __restrict__ vsum)
{
    const int tid = threadIdx.x, bx = blockIdx.x;
    if (bx < 16) {
        __shared__ float ks[64][66];
        __shared__ float wqs[64][36];
        const int b = bx >> 2, kq = bx & 3;
        #pragma unroll
        for (int i = 0; i < 4; ++i) {
            int f4 = tid + i * 256;
            int j = f4 >> 4, t4 = f4 & 15;
            float4 v = *reinterpret_cast<const float4*>(key64T + (size_t)b * 4096 + (size_t)j * 64 + 4 * t4);
            *reinterpret_cast<float4*>(&ks[j][4 * t4]) = v;
        }
        #pragma unroll
        for (int i = 0; i < 2; ++i) {
            int f4 = tid + i * 256;
            int j = f4 >> 3, kk = f4 & 7;
            float4 v = *reinterpret_cast<const float4*>(Wq + (size_t)j * EE + kq * 32 + 4 * kk);
            *reinterpret_cast<float4*>(&wqs[j][4 * kk]) = v;
        }
        __syncthreads();
        const int t0 = (tid >> 3) * 2, k0 = (tid & 7) * 4;
        float acc[2][4] = {};
        #pragma unroll
        for (int j = 0; j < 64; ++j) {
            float4 w4 = *reinterpret_cast<const float4*>(&wqs[j][k0]);
            float kv0 = ks[j][t0], kv1 = ks[j][t0 + 1];
            acc[0][0] = fmaf(kv0, w4.x, acc[0][0]);
            acc[0][1] = fmaf(kv0, w4.y, acc[0][1]);
            acc[0][2] = fmaf(kv0, w4.z, acc[0][2]);
            acc[0][3] = fmaf(kv0, w4.w, acc[0][3]);
            acc[1][0] = fmaf(kv1, w4.x, acc[1][0]);
            acc[1][1] = fmaf(kv1, w4.y, acc[1][1]);
            acc[1][2] = fmaf(kv1, w4.z, acc[1][2]);
            acc[1][3] = fmaf(kv1, w4.w, acc[1][3]);
        }
        #pragma unroll
        for (int dt = 0; dt < 2; ++dt) {
            unsigned short h0 = f2bf(acc[dt][0]), h1 = f2bf(acc[dt][1]);
            unsigned short h2 = f2bf(acc[dt][2]), h3 = f2bf(acc[dt][3]);
            ushort4 hv = make_ushort4(h0, h1, h2, h3);
            ushort4 lv = make_ushort4(f2bf(acc[dt][0] - bf2f(h0)),
                                      f2bf(acc[dt][1] - bf2f(h1)),
                                      f2bf(acc[dt][2] - bf2f(h2)),
                                      f2bf(acc[dt][3] - bf2f(h3)));
            const size_t off = (size_t)b * 8192 + (size_t)(t0 + dt) * 128 + kq * 32 + k0;
            *reinterpret_cast<ushort4*>(Mth + off) = hv;
            *reinterpret_cast<ushort4*>(Mtl + off) = lv;
        }
    } else {
        __shared__ float xsum[128];
        const int b = bx - 16;
        if (tid < 128) {
            float s = 0.f;
            #pragma unroll 8
            for (int i = 0; i < 64; ++i) s += xpart[((size_t)b * 64 + i) * 128 + tid];
            xsum[tid] = s;
        }
        __syncthreads();
        if (tid < 128) {
            float a = 0.f;
            #pragma unroll 8
            for (int e = 0; e < 128; e += 4) {
                float4 w = *reinterpret_cast<const float4*>(Wv + (size_t)tid * EE + e);
                a = fmaf(xsum[e + 0], w.x, a);
                a = fmaf(xsum[e + 1], w.y, a);
                a = fmaf(xsum[e + 2], w.z, a);
                a = fmaf(xsum[e + 3], w.w, a);
            }
            vsum[(size_t)b * EE + tid] = a;
        }
    }
}

// ---------------------------------------------------------------------------
// attn_main (r11, unchanged): 1 wave per block, 16 q-rows.
// ---------------------------------------------------------------------------
__global__ __launch_bounds__(64)
void attn_main(const float* __restrict__ x, const short* __restrict__ Mth,
               const short* __restrict__ Mtl, const short* __restrict__ Vt,
               const float* __restrict__ vsum, float* __restrict__ out)
{
    __shared__ float Plds[16][68];
    const int l = threadIdx.x;
    const int b = blockIdx.y;
    const int s0 = blockIdx.x * 16;
    const int lm = l & 15, lg = l >> 4;

    bf16x8 xh[4], xl[4];
    const float* xrow = x + ((size_t)b * SS + s0 + lm) * EE + lg * 8;
    #pragma unroll
    for (int kt = 0; kt < 4; ++kt)
        split8(xrow + kt * 32, xh[kt], xl[kt]);

    f32x4 sa[4];
    const short* mh_base = Mth + (size_t)b * 8192 + lg * 8;
    const short* ml_base = Mtl + (size_t)b * 8192 + lg * 8;
    #pragma unroll
    for (int ct = 0; ct < 4; ++ct) {
        f32x4 a = {0.f, 0.f, 0.f, 0.f};
        const size_t trow = (size_t)(ct * 16 + lm) * 128;
        #pragma unroll
        for (int kt = 0; kt < 4; ++kt) {
            bf16x8 mh = *reinterpret_cast<const bf16x8*>(mh_base + trow + kt * 32);
            bf16x8 ml = *reinterpret_cast<const bf16x8*>(ml_base + trow + kt * 32);
            a = __builtin_amdgcn_mfma_f32_16x16x32_bf16(xh[kt], mh, a, 0, 0, 0);
            a = __builtin_amdgcn_mfma_f32_16x16x32_bf16(xl[kt], mh, a, 0, 0, 0);
            a = __builtin_amdgcn_mfma_f32_16x16x32_bf16(xh[kt], ml, a, 0, 0, 0);
        }
        sa[ct] = a;
    }

    float e[4], iz[4];
    #pragma unroll
    for (int r = 0; r < 4; ++r) {
        float m = fmaxf(fmaxf(sa[0][r], sa[1][r]), fmaxf(sa[2][r], sa[3][r]));
        #pragma unroll
        for (int o = 1; o < 16; o <<= 1) m = fmaxf(m, __shfl_xor(m, o));
        m = fmaxf(m, 0.f);
        float w0 = __expf(sa[0][r] - m), w1 = __expf(sa[1][r] - m);
        float w2 = __expf(sa[2][r] - m), w3 = __expf(sa[3][r] - m);
        sa[0][r] = w0; sa[1][r] = w1; sa[2][r] = w2; sa[3][r] = w3;
        float z = (w0 + w1) + (w2 + w3);
        #pragma unroll
        for (int o = 1; o < 16; o <<= 1) z += __shfl_xor(z, o);
        e[r] = __expf(-m);
        z += 4032.f * e[r];
        iz[r] = 1.f / z;
    }

    #pragma unroll
    for (int ct = 0; ct < 4; ++ct)
        #pragma unroll
        for (int r = 0; r < 4; ++r)
            Plds[lg * 4 + r][ct * 16 + lm] = sa[ct][r];
    bf16x8 pf[2];
    #pragma unroll
    for (int kt2 = 0; kt2 < 2; ++kt2) {
        const float* pr = &Plds[lm][kt2 * 32 + lg * 8];
        #pragma unroll
        for (int i = 0; i < 8; ++i) pf[kt2][i] = (short)f2bf(pr[i]);
    }

    const short* vb = Vt + (size_t)b * 8192 + lg * 8;
    const float* vsb = vsum + (size_t)b * EE;
    const size_t obase = ((size_t)b * SS + s0) * EE;
    #pragma unroll
    for (int ct = 0; ct < 8; ++ct) {
        const int col = ct * 16 + lm;
        bf16x8 v0 = *reinterpret_cast<const bf16x8*>(vb + (size_t)col * 64);
        bf16x8 v1 = *reinterpret_cast<const bf16x8*>(vb + (size_t)col * 64 + 32);
        f32x4 a = {0.f, 0.f, 0.f, 0.f};
        a = __builtin_amdgcn_mfma_f32_16x16x32_bf16(pf[0], v0, a, 0, 0, 0);
        a = __builtin_amdgcn_mfma_f32_16x16x32_bf16(pf[1], v1, a, 0, 0, 0);
        const float vs = vsb[col];
        #pragma unroll
        for (int r = 0; r < 4; ++r)
            out[obase + (size_t)(lg * 4 + r) * EE + col] = (a[r] + e[r] * vs) * iz[r];
    }
}

// ---------------------------------------------------------------------------
extern "C" void kernel_launch(void* const* d_in, const int* in_sizes, int n_in,
                              void* d_out, int out_size, void* d_ws, size_t ws_size,
                              hipStream_t stream)
{
    const float* x  = (const float*)d_in[0];
    const float* Wk = (const float*)d_in[1];
    const float* Wq = (const float*)d_in[2];
    const float* Wv = (const float*)d_in[3];
    float* out = (float*)d_out;

    float* ws = (float*)d_ws;
    float* key64T = ws;                       // 4*64*64   = 16384 f32
    float* xpart  = key64T + 16384;           // 4*64*128  = 32768 f32
    float* vsum   = xpart + 32768;            // 4*128     = 512 f32
    unsigned short* Mth = (unsigned short*)(vsum + 512);   // 4*64*128 bf16
    unsigned short* Mtl = Mth + 32768;                     // 4*64*128 bf16
    unsigned short* Vt  = Mtl + 32768;                     // 4*128*64 bf16

    prep1<<<268, 256, 0, stream>>>(x, Wk, Wv, Vt, key64T, xpart);
    prep2<<<20, 256, 0, stream>>>(Wq, Wv, key64T, xpart, Mth, Mtl, vsum);
    attn_main<<<dim3(SS / 16, BB), 64, 0, stream>>>(
        x, (const short*)Mth, (const short*)Mtl, (const short*)Vt, vsum, out);
}

// Round 13
// 25.810 us; speedup vs baseline: 1.4107x; 1.0777x over previous
//
#include <hip/hip_runtime.h>

#define BB 4
#define SS 4096
#define EE 128

typedef __attribute__((ext_vector_type(8))) short bf16x8;
typedef __attribute__((ext_vector_type(4))) float f32x4;

__device__ __forceinline__ unsigned short f2bf(float f) {
    unsigned u = __float_as_uint(f);
    u = (u + 0x7FFFu + ((u >> 16) & 1u)) >> 16;
    return (unsigned short)u;
}
__device__ __forceinline__ float bf2f(unsigned short h) {
    return __uint_as_float(((unsigned)h) << 16);
}
// round-to-nearest split
__device__ __forceinline__ void split8(const float* p, bf16x8& h, bf16x8& l) {
    float4 v0 = *reinterpret_cast<const float4*>(p);
    float4 v1 = *reinterpret_cast<const float4*>(p + 4);
    float f[8] = {v0.x, v0.y, v0.z, v0.w, v1.x, v1.y, v1.z, v1.w};
    #pragma unroll
    for (int i = 0; i < 8; ++i) {
        unsigned short hb = f2bf(f[i]);
        h[i] = (short)hb;
        l[i] = (short)f2bf(f[i] - bf2f(hb));
    }
}
// cheap truncating split (prep1 B-operand)
__device__ __forceinline__ void split8t(const float* p, bf16x8& h, bf16x8& l) {
    float4 v0 = *reinterpret_cast<const float4*>(p);
    float4 v1 = *reinterpret_cast<const float4*>(p + 4);
    float f[8] = {v0.x, v0.y, v0.z, v0.w, v1.x, v1.y, v1.z, v1.w};
    #pragma unroll
    for (int i = 0; i < 8; ++i) {
        unsigned hb = __float_as_uint(f[i]) >> 16;
        h[i] = (short)hb;
        float lo = f[i] - __uint_as_float(hb << 16);
        l[i] = (short)(__float_as_uint(lo) >> 16);
    }
}
// 3-product split-bf16 MFMA: ~f32 accuracy (drops lo*lo)
__device__ __forceinline__ f32x4 mfma3(bf16x8 ah, bf16x8 al, bf16x8 bh, bf16x8 bl, f32x4 c) {
    c = __builtin_amdgcn_mfma_f32_16x16x32_bf16(ah, bh, c, 0, 0, 0);
    c = __builtin_amdgcn_mfma_f32_16x16x32_bf16(al, bh, c, 0, 0, 0);
    c = __builtin_amdgcn_mfma_f32_16x16x32_bf16(ah, bl, c, 0, 0, 0);
    return c;
}

// ---------------------------------------------------------------------------
// prep1 (r12, unchanged): blocks [0,256): xpart chunk column-sums;
//   blocks [256,268): MFMA 64x64 GEMMs (row-major LDS staging):
//     role 0/1: Vt[b][v][t] = bf16( x64 @ Wv^T );  role 2: masked key64T f32.
// ---------------------------------------------------------------------------
__global__ __launch_bounds__(256, 2)
void prep1(const float* __restrict__ x, const float* __restrict__ Wk,
           const float* __restrict__ Wv,
           unsigned short* __restrict__ Vt, float* __restrict__ key64T,
           float* __restrict__ xpart)
{
    __shared__ float xs[64][132];
    __shared__ float ws[64][132];
    const int tid = threadIdx.x;
    const int bx = blockIdx.x;

    if (bx < 256) {
        __shared__ float xred[2][128];
        const int b = bx >> 6, i = bx & 63;
        const size_t base = ((size_t)b * SS + 64 + (size_t)i * 63) * EE;
        const int col = tid & 127, rg = tid >> 7;
        float s = 0.f;
        for (int r = rg; r < 63; r += 2)
            s += x[base + (size_t)r * EE + col];
        xred[rg][col] = s;
        __syncthreads();
        if (tid < 128)
            xpart[((size_t)b * 64 + i) * 128 + tid] = xred[0][tid] + xred[1][tid];
        return;
    }

    const int idx = bx - 256;
    const int b = idx / 3, role = idx % 3;
    const float* Wbase = (role == 0) ? Wv : (role == 1) ? (Wv + 64 * EE) : Wk;

    #pragma unroll
    for (int i = 0; i < 8; ++i) {
        int f4 = tid + i * 256;
        int row = f4 >> 5, kq = f4 & 31;
        *reinterpret_cast<float4*>(&xs[row][4 * kq]) =
            *reinterpret_cast<const float4*>(x + ((size_t)b * SS + row) * EE + 4 * kq);
    }
    #pragma unroll
    for (int i = 0; i < 8; ++i) {
        int f4 = tid + i * 256;
        int row = f4 >> 5, kq = f4 & 31;
        *reinterpret_cast<float4*>(&ws[row][4 * kq]) =
            *reinterpret_cast<const float4*>(Wbase + (size_t)row * EE + 4 * kq);
    }
    __syncthreads();

    const int l = tid & 63, w = tid >> 6;
    const int lm = l & 15, lg = l >> 4;
    const int t0 = w * 16;

    bf16x8 xh[4], xl[4];
    #pragma unroll
    for (int kt = 0; kt < 4; ++kt)
        split8(&xs[t0 + lm][kt * 32 + lg * 8], xh[kt], xl[kt]);

    #pragma unroll
    for (int ct = 0; ct < 4; ++ct) {
        f32x4 a = {0.f, 0.f, 0.f, 0.f};
        #pragma unroll
        for (int kt = 0; kt < 4; ++kt) {
            bf16x8 bh, bl;
            split8t(&ws[ct * 16 + lm][kt * 32 + lg * 8], bh, bl);
            a = mfma3(xh[kt], xl[kt], bh, bl, a);
        }
        const int col = ct * 16 + lm;
        if (role <= 1) {
            const int voff = role * 64;
            ushort4 pk = make_ushort4(f2bf(a[0]), f2bf(a[1]), f2bf(a[2]), f2bf(a[3]));
            *reinterpret_cast<ushort4*>(Vt + (size_t)b * 8192 +
                                        (size_t)(voff + col) * 64 + t0 + lg * 4) = pk;
        } else {
            const int tb = t0 + lg * 4;
            float4 kv = make_float4((tb + 0 <= col) ? a[0] : 0.f,
                                    (tb + 1 <= col) ? a[1] : 0.f,
                                    (tb + 2 <= col) ? a[2] : 0.f,
                                    (tb + 3 <= col) ? a[3] : 0.f);
            *reinterpret_cast<float4*>(key64T + ((size_t)b * 64 + col) * 64 + tb) = kv;
        }
    }
}

// ---------------------------------------------------------------------------
// prep2 (r12, unchanged): blocks [0,16): Mt bf16 hi/lo from key64T;
//        blocks [16,20): vsum[b] = (sum_i xpart[b][i]) @ Wv^T  (f32)
// ---------------------------------------------------------------------------
__global__ __launch_bounds__(256)
void prep2(const float* __restrict__ Wq, const float* __restrict__ Wv,
           const float* __restrict__ key64T, const float* __restrict__ xpart,
           unsigned short* __restrict__ Mth, unsigned short* __restrict__ Mtl,
           float* __restrict__ vsum)
{
    const int tid = threadIdx.x, bx = blockIdx.x;
    if (bx < 16) {
        __shared__ float ks[64][66];
        __shared__ float wqs[64][36];
        const int b = bx >> 2, kq = bx & 3;
        #pragma unroll
        for (int i = 0; i < 4; ++i) {
            int f4 = tid + i * 256;
            int j = f4 >> 4, t4 = f4 & 15;
            float4 v = *reinterpret_cast<const float4*>(key64T + (size_t)b * 4096 + (size_t)j * 64 + 4 * t4);
            *reinterpret_cast<float4*>(&ks[j][4 * t4]) = v;
        }
        #pragma unroll
        for (int i = 0; i < 2; ++i) {
            int f4 = tid + i * 256;
            int j = f4 >> 3, kk = f4 & 7;
            float4 v = *reinterpret_cast<const float4*>(Wq + (size_t)j * EE + kq * 32 + 4 * kk);
            *reinterpret_cast<float4*>(&wqs[j][4 * kk]) = v;
        }
        __syncthreads();
        const int t0 = (tid >> 3) * 2, k0 = (tid & 7) * 4;
        float acc[2][4] = {};
        #pragma unroll
        for (int j = 0; j < 64; ++j) {
            float4 w4 = *reinterpret_cast<const float4*>(&wqs[j][k0]);
            float kv0 = ks[j][t0], kv1 = ks[j][t0 + 1];
            acc[0][0] = fmaf(kv0, w4.x, acc[0][0]);
            acc[0][1] = fmaf(kv0, w4.y, acc[0][1]);
            acc[0][2] = fmaf(kv0, w4.z, acc[0][2]);
            acc[0][3] = fmaf(kv0, w4.w, acc[0][3]);
            acc[1][0] = fmaf(kv1, w4.x, acc[1][0]);
            acc[1][1] = fmaf(kv1, w4.y, acc[1][1]);
            acc[1][2] = fmaf(kv1, w4.z, acc[1][2]);
            acc[1][3] = fmaf(kv1, w4.w, acc[1][3]);
        }
        #pragma unroll
        for (int dt = 0; dt < 2; ++dt) {
            unsigned short h0 = f2bf(acc[dt][0]), h1 = f2bf(acc[dt][1]);
            unsigned short h2 = f2bf(acc[dt][2]), h3 = f2bf(acc[dt][3]);
            ushort4 hv = make_ushort4(h0, h1, h2, h3);
            ushort4 lv = make_ushort4(f2bf(acc[dt][0] - bf2f(h0)),
                                      f2bf(acc[dt][1] - bf2f(h1)),
                                      f2bf(acc[dt][2] - bf2f(h2)),
                                      f2bf(acc[dt][3] - bf2f(h3)));
            const size_t off = (size_t)b * 8192 + (size_t)(t0 + dt) * 128 + kq * 32 + k0;
            *reinterpret_cast<ushort4*>(Mth + off) = hv;
            *reinterpret_cast<ushort4*>(Mtl + off) = lv;
        }
    } else {
        __shared__ float xsum[128];
        const int b = bx - 16;
        if (tid < 128) {
            float s = 0.f;
            #pragma unroll 8
            for (int i = 0; i < 64; ++i) s += xpart[((size_t)b * 64 + i) * 128 + tid];
            xsum[tid] = s;
        }
        __syncthreads();
        if (tid < 128) {
            float a = 0.f;
            #pragma unroll 8
            for (int e = 0; e < 128; e += 4) {
                float4 w = *reinterpret_cast<const float4*>(Wv + (size_t)tid * EE + e);
                a = fmaf(xsum[e + 0], w.x, a);
                a = fmaf(xsum[e + 1], w.y, a);
                a = fmaf(xsum[e + 2], w.z, a);
                a = fmaf(xsum[e + 3], w.w, a);
            }
            vsum[(size_t)b * EE + tid] = a;
        }
    }
}

// ---------------------------------------------------------------------------
// attn_main: 256 blocks x 4 waves (64 rows/block) — amortizes Mth/Mtl/Vt
// L2 reads 4x vs the 1-wave shape (r9-vs-r10 A/B: -1.5us). Per wave: 16 rows,
// S = x@Mt split-MFMA, softmax (+4032 zero cols), P relayout, PV + vsum term.
// ---------------------------------------------------------------------------
__global__ __launch_bounds__(256, 2)
void attn_main(const float* __restrict__ x, const short* __restrict__ Mth,
               const short* __restrict__ Mtl, const short* __restrict__ Vt,
               const float* __restrict__ vsum, float* __restrict__ out)
{
    __shared__ float Plds[64][68];
    __shared__ float vsS[128];
    const int tid = threadIdx.x;
    const int bx = blockIdx.x;
    const int b = bx >> 6;
    const int s0 = (bx & 63) * 64;
    const int l = tid & 63, w = tid >> 6;
    const int lm = l & 15, lg = l >> 4;
    const int srow = s0 + w * 16;

    if (tid < 128) vsS[tid] = vsum[(size_t)b * EE + tid];

    // x A-frags (hi/lo split)
    bf16x8 xh[4], xl[4];
    const float* xrow = x + ((size_t)b * SS + srow + lm) * EE + lg * 8;
    #pragma unroll
    for (int kt = 0; kt < 4; ++kt)
        split8(xrow + kt * 32, xh[kt], xl[kt]);

    // S = x @ Mt : 4 col-tiles x (4 k-tiles x 3 split-mfma)
    f32x4 sa[4];
    const short* mh_base = Mth + (size_t)b * 8192 + lg * 8;
    const short* ml_base = Mtl + (size_t)b * 8192 + lg * 8;
    #pragma unroll
    for (int ct = 0; ct < 4; ++ct) {
        f32x4 a = {0.f, 0.f, 0.f, 0.f};
        const size_t trow = (size_t)(ct * 16 + lm) * 128;
        #pragma unroll
        for (int kt = 0; kt < 4; ++kt) {
            bf16x8 mh = *reinterpret_cast<const bf16x8*>(mh_base + trow + kt * 32);
            bf16x8 ml = *reinterpret_cast<const bf16x8*>(ml_base + trow + kt * 32);
            a = __builtin_amdgcn_mfma_f32_16x16x32_bf16(xh[kt], mh, a, 0, 0, 0);
            a = __builtin_amdgcn_mfma_f32_16x16x32_bf16(xl[kt], mh, a, 0, 0, 0);
            a = __builtin_amdgcn_mfma_f32_16x16x32_bf16(xh[kt], ml, a, 0, 0, 0);
        }
        sa[ct] = a;
    }

    // softmax over 4096 cols (64 real + 4032 exact zeros)
    float e[4], iz[4];
    #pragma unroll
    for (int r = 0; r < 4; ++r) {
        float m = fmaxf(fmaxf(sa[0][r], sa[1][r]), fmaxf(sa[2][r], sa[3][r]));
        #pragma unroll
        for (int o = 1; o < 16; o <<= 1) m = fmaxf(m, __shfl_xor(m, o));
        m = fmaxf(m, 0.f);
        float w0 = __expf(sa[0][r] - m), w1 = __expf(sa[1][r] - m);
        float w2 = __expf(sa[2][r] - m), w3 = __expf(sa[3][r] - m);
        sa[0][r] = w0; sa[1][r] = w1; sa[2][r] = w2; sa[3][r] = w3;
        float z = (w0 + w1) + (w2 + w3);
        #pragma unroll
        for (int o = 1; o < 16; o <<= 1) z += __shfl_xor(z, o);
        e[r] = __expf(-m);
        z += 4032.f * e[r];
        iz[r] = 1.f / z;
    }

    // P relayout (per-wave rows): C/D layout -> A-frag layout via LDS
    __syncthreads();   // vsS visible; Plds regions are per-wave disjoint
    #pragma unroll
    for (int ct = 0; ct < 4; ++ct)
        #pragma unroll
        for (int r = 0; r < 4; ++r)
            Plds[w * 16 + lg * 4 + r][ct * 16 + lm] = sa[ct][r];
    bf16x8 pf[2];
    #pragma unroll
    for (int kt2 = 0; kt2 < 2; ++kt2) {
        const float* pr = &Plds[w * 16 + lm][kt2 * 32 + lg * 8];
        #pragma unroll
        for (int i = 0; i < 8; ++i) pf[kt2][i] = (short)f2bf(pr[i]);
    }

    // PV + vsum term + normalize + store
    const short* vb = Vt + (size_t)b * 8192 + lg * 8;
    const size_t obase = ((size_t)b * SS + srow) * EE;
    #pragma unroll
    for (int ct = 0; ct < 8; ++ct) {
        const int col = ct * 16 + lm;
        bf16x8 v0 = *reinterpret_cast<const bf16x8*>(vb + (size_t)col * 64);
        bf16x8 v1 = *reinterpret_cast<const bf16x8*>(vb + (size_t)col * 64 + 32);
        f32x4 a = {0.f, 0.f, 0.f, 0.f};
        a = __builtin_amdgcn_mfma_f32_16x16x32_bf16(pf[0], v0, a, 0, 0, 0);
        a = __builtin_amdgcn_mfma_f32_16x16x32_bf16(pf[1], v1, a, 0, 0, 0);
        const float vs = vsS[col];
        #pragma unroll
        for (int r = 0; r < 4; ++r)
            out[obase + (size_t)(lg * 4 + r) * EE + col] = (a[r] + e[r] * vs) * iz[r];
    }
}

// ---------------------------------------------------------------------------
extern "C" void kernel_launch(void* const* d_in, const int* in_sizes, int n_in,
                              void* d_out, int out_size, void* d_ws, size_t ws_size,
                              hipStream_t stream)
{
    const float* x  = (const float*)d_in[0];
    const float* Wk = (const float*)d_in[1];
    const float* Wq = (const float*)d_in[2];
    const float* Wv = (const float*)d_in[3];
    float* out = (float*)d_out;

    float* ws = (float*)d_ws;
    float* key64T = ws;                       // 4*64*64   = 16384 f32
    float* xpart  = key64T + 16384;           // 4*64*128  = 32768 f32
    float* vsum   = xpart + 32768;            // 4*128     = 512 f32
    unsigned short* Mth = (unsigned short*)(vsum + 512);   // 4*64*128 bf16
    unsigned short* Mtl = Mth + 32768;                     // 4*64*128 bf16
    unsigned short* Vt  = Mtl + 32768;                     // 4*128*64 bf16

    prep1<<<268, 256, 0, stream>>>(x, Wk, Wv, Vt, key64T, xpart);
    prep2<<<20, 256, 0, stream>>>(Wq, Wv, key64T, xpart, Mth, Mtl, vsum);
    attn_main<<<256, 256, 0, stream>>>(
        x, (const short*)Mth, (const short*)Mtl, (const short*)Vt, vsum, out);
}